// Round 11
// baseline (418.697 us; speedup 1.0000x reference)
//
#include <hip/hip_runtime.h>
#include <hip/hip_bf16.h>
#include <math.h>

#define NPTS 30000
#define KNN  16
#define NB   30          // batches (of 2 points) per block
#define GRID 500         // 500 * 60 pts = 30000 exactly

typedef __attribute__((ext_vector_type(8)))  __bf16 bf16x8;
typedef __attribute__((ext_vector_type(16))) float  f32x16;
typedef __attribute__((ext_vector_type(4)))  float  f32x4;

__device__ __forceinline__ unsigned short f2bf(float x) {
    __bf16 b = (__bf16)x;                       // native cvt (RNE)
    return __builtin_bit_cast(unsigned short, b);
}
__device__ __forceinline__ unsigned pk2(float a, float b) {
    return (unsigned)f2bf(a) | ((unsigned)f2bf(b) << 16);
}
__device__ __forceinline__ float bf_lo(unsigned u) { return __builtin_bit_cast(float, u << 16); }
__device__ __forceinline__ float bf_hi(unsigned u) { return __builtin_bit_cast(float, u & 0xffff0000u); }
// tanh-form GELU: x*(1 - 1/(exp(1.5958*(x+0.044715x^3)) + 1))
__device__ __forceinline__ float gelu_t(float x) {
    float x2 = x * x;
    float u  = x * fmaf(0.07135481624f, x2, 1.59576912161f);
    float e  = __expf(u);
    float r  = __builtin_amdgcn_rcpf(e + 1.0f);
    return fmaf(-x, r, x);
}

// ---- prep: bf16 weight layouts in ws (identical to R7/R10) ----
__global__ void prep_w(const float* __restrict__ W1, const float* __restrict__ W2,
                       const float* __restrict__ Ws,
                       unsigned short* __restrict__ w1dt, unsigned short* __restrict__ w2t,
                       unsigned short* __restrict__ wcst) {
    int t = blockIdx.x * 256 + threadIdx.x;          // t < 65536
    {   int e = t >> 8, c = t & 255;
        w2t[t] = f2bf(W2[c * 256 + e]); }
    {   int col = t >> 7, k = t & 127;
        float v = (col < 256) ? W1[k * 256 + col] : Ws[k * 256 + (col - 256)];
        wcst[t] = f2bf(v); }
    if (t < 32768) {
        int d = t >> 7, k = t & 127;
        w1dt[t] = f2bf(W1[(128 + k) * 256 + d]); }
}

// R10 structure (proven correct/deterministic) with ONE delta: W2 fragments are
// NOT persistent — reloaded from L2 each G2 in 4-frag chunks behind an opaque
// pointer, cutting total regs (VGPR+AGPR) under the 128 occupancy tier
// (R10 evidence: VGPR 120 + >=16 AGPR -> 256-tier -> 2 waves/SIMD stuck).
__global__ __launch_bounds__(512) void edgeconv_main(
    const float* __restrict__ feat, const int* __restrict__ knn,
    const unsigned short* __restrict__ w1dt, const unsigned short* __restrict__ w2t,
    const unsigned short* __restrict__ wcst,
    const float* __restrict__ b1, const float* __restrict__ b2,
    const float* __restrict__ bs,
    const float* __restrict__ gamma, const float* __restrict__ beta,
    float* __restrict__ out)
{
    __shared__ __align__(16) unsigned char  s_edge[2][32 * 256];   // 16 KB diff-edge bf16, swz (row&15)<<4
    __shared__ __align__(16) unsigned char  s_h[2][32 * 512];      // 32 KB h bf16, swz (row&31)<<4
    __shared__ __align__(16) unsigned short s_c2[2][8][512];       // 16 KB [buf][pt][cterm|skip]
    __shared__ __align__(16) float s_agg[2][2][256];               //  4 KB channel max
    // total 68 KB -> 2 blocks/CU (if regs <= 128 total)

    const int lane = threadIdx.x & 63;
    const int wv   = threadIdx.x >> 6;      // 0..7
    const int l31  = lane & 31;
    const int lh   = lane >> 5;
    const int l15  = lane & 15;
    const int l4   = lane >> 4;
    const int pblock = blockIdx.x * 60;
    const int chb = wv * 32;                // this wave's 32 channels (both GEMMs)

    // persistent: only W1d fragments (32 VGPR)
    bf16x8 w1f[8];
    #pragma unroll
    for (int ks = 0; ks < 8; ++ks)
        w1f[ks] = *(const bf16x8*)(w1dt + (chb + l31) * 128 + ks * 16 + lh * 8);

    // c2-pass for 8-point super s: cterm+b1 (cols 0:256) | skip+bs+b2 (256:512)
    auto c2pass = [&](int s) {
        const int buf = s & 1;
        bf16x8 af[4];
        #pragma unroll
        for (int ks = 0; ks < 4; ++ks) {
            int pi = s * 8 + (l15 & 7);                // A rows 8-15 dup 0-7 (never read)
            if (pi > 59) pi = 59;                      // clamp (super 7)
            const float* fp = feat + (long)(pblock + pi) * 128 + ks * 32 + l4 * 8;
            float4 f0 = *(const float4*)fp;
            float4 f1 = *(const float4*)(fp + 4);
            uint4 u;
            u.x = pk2(f0.x, f0.y); u.y = pk2(f0.z, f0.w);
            u.z = pk2(f1.x, f1.y); u.w = pk2(f1.z, f1.w);
            af[ks] = __builtin_bit_cast(bf16x8, u);
        }
        #pragma unroll
        for (int j = 0; j < 4; ++j) {
            const int ct  = wv * 4 + j;                // 0..31
            const int col = ct * 16 + l15;
            float bias = (ct < 16) ? b1[col] : (bs[col - 256] + b2[col - 256]);
            f32x4 acc = {bias, bias, bias, bias};
            #pragma unroll
            for (int ks = 0; ks < 4; ++ks) {
                bf16x8 bf = *(const bf16x8*)(wcst + col * 128 + ks * 32 + l4 * 8);
                acc = __builtin_amdgcn_mfma_f32_16x16x32_bf16(af[ks], bf, acc, 0, 0, 0);
            }
            #pragma unroll
            for (int r = 0; r < 4; ++r) {
                int prow = l4 * 4 + r;                 // D row = point-in-super
                if (prow < 8) s_c2[buf][prow][col] = f2bf(acc[r]);
            }
        }
    };

    // stage batch bt into edge[bt&1]: wave loads+writes 4 rows
    auto stage = [&](int bt) {
        const int st_pt = wv >> 2;                     // 0..1
        const int st_kb = (wv & 3) * 4;
        const int n = pblock + bt * 2 + st_pt;
        float2 cc = *(const float2*)(feat + (long)n * 128 + lane * 2);
        int idx[4];
        #pragma unroll
        for (int kk = 0; kk < 4; ++kk) idx[kk] = knn[n * 16 + st_kb + kk];
        #pragma unroll
        for (int kk = 0; kk < 4; ++kk) {
            float2 nb = *(const float2*)(feat + (long)idx[kk] * 128 + lane * 2);
            int row = st_pt * 16 + st_kb + kk;
            unsigned v = pk2(nb.x - cc.x, nb.y - cc.y);
            *(unsigned*)(s_edge[bt & 1] + row * 256 + ((unsigned)(lane * 4) ^ (unsigned)((row & 15) << 4))) = v;
        }
    };

    // ---- prologue ----
    stage(0);
    c2pass(0);
    __syncthreads();

    const f32x16 z16 = (f32x16)0.0f;

    #pragma unroll 1
    for (int i = 0; i <= NB + 1; ++i) {
        // ---- B) GEMM2(i-1): eo = h . W2; max over each point's 16 rows -> s_agg ----
        if (i >= 1 && i <= NB) {
            const int bt = i - 1;
            const int row = l31;
            const unsigned swz = (unsigned)((row & 31) << 4);
            const unsigned rb = (unsigned)row * 512u;
            // opaque base pointer: stops the compiler hoisting the 16 W2 frags
            // out of the loop into 64 persistent VGPRs (the R10 occupancy killer)
            const unsigned short* w2p = w2t + (chb + l31) * 256 + lh * 8;
            asm volatile("" : "+v"(w2p));
            f32x16 a2 = z16;
            #pragma unroll
            for (int half = 0; half < 4; ++half) {
                bf16x8 wf[4];
                #pragma unroll
                for (int k = 0; k < 4; ++k)
                    wf[k] = *(const bf16x8*)(w2p + (half * 4 + k) * 16);
                #pragma unroll
                for (int k = 0; k < 4; ++k) {
                    const int ks = half * 4 + k;
                    bf16x8 hf = *(const bf16x8*)(s_h[bt & 1] + rb + ((unsigned)(ks * 32 + lh * 16) ^ swz));
                    a2 = __builtin_amdgcn_mfma_f32_32x32x16_bf16(hf, wf[k], a2, 0, 0, 0);
                }
            }
            float m0 = a2[0], m1 = a2[8];
            #pragma unroll
            for (int r = 1; r < 8; ++r) {
                m0 = fmaxf(m0, a2[r]);        // regs 0-7  = h rows 0..15  (point 0)
                m1 = fmaxf(m1, a2[8 + r]);    // regs 8-15 = h rows 16..31 (point 1)
            }
            m0 = fmaxf(m0, __shfl_xor(m0, 32));
            m1 = fmaxf(m1, __shfl_xor(m1, 32));
            if (lh == 0) {
                s_agg[bt & 1][0][chb + l31] = m0;
                s_agg[bt & 1][1][chb + l31] = m1;
            }
        }

        // ---- C) GEMM1(i): h = gelu(edge_diff . W1d + cterm) -> s_h[i&1] ----
        if (i < NB) {
            const int sB = (i >> 2) & 1;
            const int row = l31;
            f32x16 acc1 = z16;
            {
                const unsigned swz = (unsigned)((row & 15) << 4);
                const unsigned rb = (unsigned)row * 256u;
                #pragma unroll
                for (int ks = 0; ks < 8; ++ks) {
                    bf16x8 bf = *(const bf16x8*)(s_edge[i & 1] + rb + ((unsigned)(ks * 32 + lh * 16) ^ swz));
                    acc1 = __builtin_amdgcn_mfma_f32_32x32x16_bf16(w1f[ks], bf, acc1, 0, 0, 0);
                }
            }
            {
                const int pt8 = (i & 3) * 2 + (l31 >> 4);
                const unsigned swz = (unsigned)((row & 31) << 4);
                #pragma unroll
                for (int g = 0; g < 4; ++g) {
                    const int ch0 = chb + 8 * g + 4 * lh;
                    uint2 c2v = *(const uint2*)(&s_c2[sB][pt8][ch0]);   // broadcast read
                    float v0 = gelu_t(acc1[4 * g + 0] + bf_lo(c2v.x));
                    float v1 = gelu_t(acc1[4 * g + 1] + bf_hi(c2v.x));
                    float v2 = gelu_t(acc1[4 * g + 2] + bf_lo(c2v.y));
                    float v3 = gelu_t(acc1[4 * g + 3] + bf_hi(c2v.y));
                    uint2 hv; hv.x = pk2(v0, v1); hv.y = pk2(v2, v3);
                    *(uint2*)(s_h[i & 1] + (unsigned)row * 512u + ((unsigned)(ch0 * 2) ^ swz)) = hv;
                }
            }
        }

        // ---- D) LayerNorm(i-2) on waves 0-1 (one point each) ----
        if (i >= 2 && wv < 2) {
            const int bt2 = i - 2;
            const int n   = pblock + bt2 * 2 + wv;
            const int sB  = (bt2 >> 2) & 1;
            const int pt8 = (bt2 & 3) * 2 + wv;
            float4 ag = *(const float4*)&s_agg[bt2 & 1][wv][lane * 4];
            uint2 sk  = *(const uint2*)(&s_c2[sB][pt8][256 + lane * 4]);
            float x0 = ag.x + bf_lo(sk.x), x1 = ag.y + bf_hi(sk.x);
            float x2 = ag.z + bf_lo(sk.y), x3 = ag.w + bf_hi(sk.y);
            float s  = x0 + x1 + x2 + x3;
            float ss = fmaf(x0, x0, fmaf(x1, x1, fmaf(x2, x2, x3 * x3)));
            #pragma unroll
            for (int off = 1; off < 64; off <<= 1) {
                s  += __shfl_xor(s, off);
                ss += __shfl_xor(ss, off);
            }
            float mu   = s * (1.0f / 256.0f);
            float var  = ss * (1.0f / 256.0f) - mu * mu;
            float rstd = rsqrtf(var + 1e-5f);
            float4 g4 = *(const float4*)&gamma[lane * 4];
            float4 b4 = *(const float4*)&beta[lane * 4];
            float4 o;
            o.x = (x0 - mu) * rstd * g4.x + b4.x;
            o.y = (x1 - mu) * rstd * g4.y + b4.y;
            o.z = (x2 - mu) * rstd * g4.z + b4.z;
            o.w = (x3 - mu) * rstd * g4.w + b4.w;
            *(float4*)&out[(long)n * 256 + lane * 4] = o;
        }

        // ---- E) c2 super s=(i>>2)+1 at i=4s-2 ----
        if ((i & 3) == 2) {
            int s = (i >> 2) + 1;
            if (s < 8) c2pass(s);
        }

        // ---- F) stage batch i+1 -> edge[(i+1)&1] ----
        if (i + 1 < NB) stage(i + 1);

        __syncthreads();
    }
}

extern "C" void kernel_launch(void* const* d_in, const int* in_sizes, int n_in,
                              void* d_out, int out_size, void* d_ws, size_t ws_size,
                              hipStream_t stream) {
    const float* feat  = (const float*)d_in[0];
    const int*   knn   = (const int*)  d_in[1];
    const float* W1    = (const float*)d_in[2];
    const float* b1    = (const float*)d_in[3];
    const float* W2    = (const float*)d_in[4];
    const float* b2    = (const float*)d_in[5];
    const float* Ws    = (const float*)d_in[6];
    const float* bs    = (const float*)d_in[7];
    const float* gamma = (const float*)d_in[8];
    const float* beta  = (const float*)d_in[9];
    float* out = (float*)d_out;

    unsigned short* w1dt = (unsigned short*)d_ws;          //  64 KB
    unsigned short* w2t  = w1dt + 32768;                   // 128 KB
    unsigned short* wcst = w2t + 65536;                    // 128 KB  (total 320 KB)

    hipLaunchKernelGGL(prep_w, dim3(256), dim3(256), 0, stream, W1, W2, Ws, w1dt, w2t, wcst);
    hipLaunchKernelGGL(edgeconv_main, dim3(GRID), dim3(512), 0, stream,
                       feat, knn, w1dt, w2t, wcst, b1, b2, bs, gamma, beta, out);
}

// Round 12
// 398.555 us; speedup vs baseline: 1.0505x; 1.0505x over previous
//
#include <hip/hip_runtime.h>
#include <hip/hip_bf16.h>
#include <math.h>

#define NPTS 30000
#define KNN  16
#define NB   30          // batches (of 2 points) per block
#define GRID 500         // 500 * 60 pts = 30000 exactly

typedef __attribute__((ext_vector_type(8)))  __bf16 bf16x8;
typedef __attribute__((ext_vector_type(16))) float  f32x16;
typedef __attribute__((ext_vector_type(4)))  float  f32x4;

__device__ __forceinline__ unsigned short f2bf(float x) {
    __bf16 b = (__bf16)x;                       // native cvt (RNE)
    return __builtin_bit_cast(unsigned short, b);
}
__device__ __forceinline__ unsigned pk2(float a, float b) {
    return (unsigned)f2bf(a) | ((unsigned)f2bf(b) << 16);
}
__device__ __forceinline__ float bf_lo(unsigned u) { return __builtin_bit_cast(float, u << 16); }
__device__ __forceinline__ float bf_hi(unsigned u) { return __builtin_bit_cast(float, u & 0xffff0000u); }
// tanh-form GELU: x*(1 - 1/(exp(1.5958*(x+0.044715x^3)) + 1))
__device__ __forceinline__ float gelu_t(float x) {
    float x2 = x * x;
    float u  = x * fmaf(0.07135481624f, x2, 1.59576912161f);
    float e  = __expf(u);
    float r  = __builtin_amdgcn_rcpf(e + 1.0f);
    return fmaf(-x, r, x);
}

// ---- prep1: bf16 weight layouts in ws ----
// w1dt[d][k] = W1[128+k][d]          (256x128)
// w2t [e][c] = W2[c][e]              (256x256)
// wcst[col][k] = col<256 ? W1[k][col] : Ws[k][col-256]   (512x128)
__global__ void prep_w(const float* __restrict__ W1, const float* __restrict__ W2,
                       const float* __restrict__ Ws,
                       unsigned short* __restrict__ w1dt, unsigned short* __restrict__ w2t,
                       unsigned short* __restrict__ wcst) {
    int t = blockIdx.x * 256 + threadIdx.x;          // t < 65536
    {   int e = t >> 8, c = t & 255;
        w2t[t] = f2bf(W2[c * 256 + e]); }
    {   int col = t >> 7, k = t & 127;
        float v = (col < 256) ? W1[k * 256 + col] : Ws[k * 256 + (col - 256)];
        wcst[t] = f2bf(v); }
    if (t < 32768) {
        int d = t >> 7, k = t & 127;
        w1dt[t] = f2bf(W1[(128 + k) * 256 + d]); }
}

// ---- prep2: per-point affine terms for ALL points (hoists c2pass out of main) ----
// cs[n][d] = bf16(b1[d] + feat[n] @ W1[:128,d])          (cterm)
// sk[n][e] = bf16(b2[e] + bs[e] + feat[n] @ Ws[:,e])     (skip)
// Block = 16 points, 8 waves; wave does 4 col-tiles of the 512-wide [cterm|skip].
__global__ __launch_bounds__(512) void prep2(
    const float* __restrict__ feat, const unsigned short* __restrict__ wcst,
    const float* __restrict__ b1, const float* __restrict__ b2,
    const float* __restrict__ bs,
    unsigned short* __restrict__ cs, unsigned short* __restrict__ sk)
{
    const int lane = threadIdx.x & 63;
    const int wv   = threadIdx.x >> 6;
    const int l15  = lane & 15;
    const int l4   = lane >> 4;
    const int pb   = blockIdx.x * 16;                 // 1875 * 16 = 30000

    bf16x8 af[4];
    #pragma unroll
    for (int ks = 0; ks < 4; ++ks) {
        const float* fp = feat + (long)(pb + l15) * 128 + ks * 32 + l4 * 8;
        float4 f0 = *(const float4*)fp;
        float4 f1 = *(const float4*)(fp + 4);
        uint4 u;
        u.x = pk2(f0.x, f0.y); u.y = pk2(f0.z, f0.w);
        u.z = pk2(f1.x, f1.y); u.w = pk2(f1.z, f1.w);
        af[ks] = __builtin_bit_cast(bf16x8, u);
    }
    #pragma unroll
    for (int j = 0; j < 4; ++j) {
        const int ct  = wv * 4 + j;                   // 0..31
        const int col = ct * 16 + l15;
        float bias = (ct < 16) ? b1[col] : (bs[col - 256] + b2[col - 256]);
        f32x4 acc = {bias, bias, bias, bias};
        #pragma unroll
        for (int ks = 0; ks < 4; ++ks) {
            bf16x8 bf = *(const bf16x8*)(wcst + col * 128 + ks * 32 + l4 * 8);
            acc = __builtin_amdgcn_mfma_f32_16x16x32_bf16(af[ks], bf, acc, 0, 0, 0);
        }
        #pragma unroll
        for (int r = 0; r < 4; ++r) {
            const int n = pb + l4 * 4 + r;            // D row = point
            if (ct < 16) cs[(long)n * 256 + col]         = f2bf(acc[r]);
            else         sk[(long)n * 256 + (col - 256)] = f2bf(acc[r]);
        }
    }
}

// Main: R10's proven loop minus c2pass/s_c2 (cterm/sk precomputed in ws).
// LDS 52 KB; regs target <=128 total (w1f 32 persistent, W2 streamed from L2).
// Per iter i, ONE barrier:
//   A) issue loads: staging(i+1), cterm(i) for C, sk(i-2) for D
//   B) GEMM2(i-1): h[(i-1)&1] . W2(streamed) -> max -> agg[(i-1)&1]
//   C) GEMM1(i):   edge[i&1] . W1d + cterm -> gelu -> h[i&1]
//   D) LN(i-2):    agg[(i-2)&1] + sk -> out   (waves 0-1)
//   F) write staged edges(i+1) -> edge[(i+1)&1]
__global__ __launch_bounds__(512) void edgeconv_main(
    const float* __restrict__ feat, const int* __restrict__ knn,
    const unsigned short* __restrict__ w1dt, const unsigned short* __restrict__ w2t,
    const unsigned short* __restrict__ cs,  const unsigned short* __restrict__ sk,
    const float* __restrict__ gamma, const float* __restrict__ beta,
    float* __restrict__ out)
{
    __shared__ __align__(16) unsigned char  s_edge[2][32 * 256];   // 16 KB, swz (row&15)<<4
    __shared__ __align__(16) unsigned char  s_h[2][32 * 512];      // 32 KB, swz (row&31)<<4
    __shared__ __align__(16) float s_agg[2][2][256];               //  4 KB
    // total 52 KB

    const int lane = threadIdx.x & 63;
    const int wv   = threadIdx.x >> 6;      // 0..7
    const int l31  = lane & 31;
    const int lh   = lane >> 5;
    const int pblock = blockIdx.x * 60;
    const int chb = wv * 32;                // this wave's 32 channels (both GEMMs)

    // persistent: W1d fragments only (32 VGPR)
    bf16x8 w1f[8];
    #pragma unroll
    for (int ks = 0; ks < 8; ++ks)
        w1f[ks] = *(const bf16x8*)(w1dt + (chb + l31) * 128 + ks * 16 + lh * 8);

    // staging role: wave stages 4 rows of point (wv>>2), neighbors (wv&3)*4..+4
    const int st_pt = wv >> 2;
    const int st_kb = (wv & 3) * 4;

    // ---- prologue: stage batch 0 (immediate) ----
    {
        const int n = pblock + st_pt;
        float2 cc = *(const float2*)(feat + (long)n * 128 + lane * 2);
        int4 iv = *(const int4*)(knn + n * 16 + st_kb);
        int idx[4] = {iv.x, iv.y, iv.z, iv.w};
        #pragma unroll
        for (int kk = 0; kk < 4; ++kk) {
            float2 nb = *(const float2*)(feat + (long)idx[kk] * 128 + lane * 2);
            int row = st_pt * 16 + st_kb + kk;
            unsigned v = pk2(nb.x - cc.x, nb.y - cc.y);
            *(unsigned*)(s_edge[0] + row * 256 + ((unsigned)(lane * 4) ^ (unsigned)((row & 15) << 4))) = v;
        }
    }
    __syncthreads();

    const f32x16 z16 = (f32x16)0.0f;

    #pragma unroll 1
    for (int i = 0; i <= NB + 1; ++i) {
        // ---- A) issue all global loads this iter needs late ----
        float2 cc; float2 nbr[4];
        const bool doStage = (i + 1 < NB);
        if (doStage) {
            const int n = pblock + (i + 1) * 2 + st_pt;
            cc = *(const float2*)(feat + (long)n * 128 + lane * 2);
            int4 iv = *(const int4*)(knn + n * 16 + st_kb);
            int idx[4] = {iv.x, iv.y, iv.z, iv.w};
            #pragma unroll
            for (int kk = 0; kk < 4; ++kk)
                nbr[kk] = *(const float2*)(feat + (long)idx[kk] * 128 + lane * 2);
        }
        uint2 ct4[4];                        // cterm for C(i): point pblock+i*2+(l31>>4)
        if (i < NB) {
            const int n_pt = pblock + i * 2 + (l31 >> 4);
            const unsigned short* cp = cs + (long)n_pt * 256 + chb + 4 * lh;
            #pragma unroll
            for (int g = 0; g < 4; ++g) ct4[g] = *(const uint2*)(cp + 8 * g);
        }
        uint2 skv;                           // skip for D(i-2): point pblock+(i-2)*2+wv
        if (i >= 2 && wv < 2) {
            const int n = pblock + (i - 2) * 2 + wv;
            skv = *(const uint2*)(sk + (long)n * 256 + lane * 4);
        }

        // ---- B) GEMM2(i-1): eo = h . W2 (streamed); max over 16 rows -> s_agg ----
        if (i >= 1 && i <= NB) {
            const int bt = i - 1;
            const unsigned swz = (unsigned)((l31 & 31) << 4);
            const unsigned rb = (unsigned)l31 * 512u;
            const unsigned short* w2p = w2t + (chb + l31) * 256 + lh * 8;
            asm volatile("" : "+v"(w2p));    // keep W2 frags transient (reg budget)
            f32x16 a2 = z16;
            #pragma unroll
            for (int half = 0; half < 4; ++half) {
                bf16x8 wf[4];
                #pragma unroll
                for (int k = 0; k < 4; ++k)
                    wf[k] = *(const bf16x8*)(w2p + (half * 4 + k) * 16);
                #pragma unroll
                for (int k = 0; k < 4; ++k) {
                    const int ks = half * 4 + k;
                    bf16x8 hf = *(const bf16x8*)(s_h[bt & 1] + rb + ((unsigned)(ks * 32 + lh * 16) ^ swz));
                    a2 = __builtin_amdgcn_mfma_f32_32x32x16_bf16(hf, wf[k], a2, 0, 0, 0);
                }
            }
            float m0 = a2[0], m1 = a2[8];
            #pragma unroll
            for (int r = 1; r < 8; ++r) {
                m0 = fmaxf(m0, a2[r]);        // regs 0-7  = rows 0..15  (point 0)
                m1 = fmaxf(m1, a2[8 + r]);    // regs 8-15 = rows 16..31 (point 1)
            }
            m0 = fmaxf(m0, __shfl_xor(m0, 32));
            m1 = fmaxf(m1, __shfl_xor(m1, 32));
            if (lh == 0) {
                s_agg[bt & 1][0][chb + l31] = m0;
                s_agg[bt & 1][1][chb + l31] = m1;
            }
        }

        // ---- C) GEMM1(i): h = gelu(edge_diff . W1d + cterm) -> s_h[i&1] ----
        if (i < NB) {
            const int row = l31;
            f32x16 acc1 = z16;
            {
                const unsigned swz = (unsigned)((row & 15) << 4);
                const unsigned rb = (unsigned)row * 256u;
                #pragma unroll
                for (int ks = 0; ks < 8; ++ks) {
                    bf16x8 bf = *(const bf16x8*)(s_edge[i & 1] + rb + ((unsigned)(ks * 32 + lh * 16) ^ swz));
                    acc1 = __builtin_amdgcn_mfma_f32_32x32x16_bf16(w1f[ks], bf, acc1, 0, 0, 0);
                }
            }
            {
                const unsigned swz = (unsigned)((row & 31) << 4);
                #pragma unroll
                for (int g = 0; g < 4; ++g) {
                    const int ch0 = chb + 8 * g + 4 * lh;
                    float v0 = gelu_t(acc1[4 * g + 0] + bf_lo(ct4[g].x));
                    float v1 = gelu_t(acc1[4 * g + 1] + bf_hi(ct4[g].x));
                    float v2 = gelu_t(acc1[4 * g + 2] + bf_lo(ct4[g].y));
                    float v3 = gelu_t(acc1[4 * g + 3] + bf_hi(ct4[g].y));
                    uint2 hv; hv.x = pk2(v0, v1); hv.y = pk2(v2, v3);
                    *(uint2*)(s_h[i & 1] + (unsigned)row * 512u + ((unsigned)(ch0 * 2) ^ swz)) = hv;
                }
            }
        }

        // ---- D) LayerNorm(i-2) on waves 0-1 ----
        if (i >= 2 && wv < 2) {
            const int bt2 = i - 2;
            const int n   = pblock + bt2 * 2 + wv;
            float4 ag = *(const float4*)&s_agg[bt2 & 1][wv][lane * 4];
            float x0 = ag.x + bf_lo(skv.x), x1 = ag.y + bf_hi(skv.x);
            float x2 = ag.z + bf_lo(skv.y), x3 = ag.w + bf_hi(skv.y);
            float s  = x0 + x1 + x2 + x3;
            float ss = fmaf(x0, x0, fmaf(x1, x1, fmaf(x2, x2, x3 * x3)));
            #pragma unroll
            for (int off = 1; off < 64; off <<= 1) {
                s  += __shfl_xor(s, off);
                ss += __shfl_xor(ss, off);
            }
            float mu   = s * (1.0f / 256.0f);
            float var  = ss * (1.0f / 256.0f) - mu * mu;
            float rstd = rsqrtf(var + 1e-5f);
            float4 g4 = *(const float4*)&gamma[lane * 4];
            float4 b4 = *(const float4*)&beta[lane * 4];
            float4 o;
            o.x = (x0 - mu) * rstd * g4.x + b4.x;
            o.y = (x1 - mu) * rstd * g4.y + b4.y;
            o.z = (x2 - mu) * rstd * g4.z + b4.z;
            o.w = (x3 - mu) * rstd * g4.w + b4.w;
            *(float4*)&out[(long)n * 256 + lane * 4] = o;
        }

        // ---- F) write staged edges -> edge[(i+1)&1] ----
        if (doStage) {
            const int bt = i + 1;
            #pragma unroll
            for (int kk = 0; kk < 4; ++kk) {
                int row = st_pt * 16 + st_kb + kk;
                unsigned v = pk2(nbr[kk].x - cc.x, nbr[kk].y - cc.y);
                *(unsigned*)(s_edge[bt & 1] + row * 256 + ((unsigned)(lane * 4) ^ (unsigned)((row & 15) << 4))) = v;
            }
        }
        __syncthreads();
    }
}

extern "C" void kernel_launch(void* const* d_in, const int* in_sizes, int n_in,
                              void* d_out, int out_size, void* d_ws, size_t ws_size,
                              hipStream_t stream) {
    const float* feat  = (const float*)d_in[0];
    const int*   knn   = (const int*)  d_in[1];
    const float* W1    = (const float*)d_in[2];
    const float* b1    = (const float*)d_in[3];
    const float* W2    = (const float*)d_in[4];
    const float* b2    = (const float*)d_in[5];
    const float* Ws    = (const float*)d_in[6];
    const float* bs    = (const float*)d_in[7];
    const float* gamma = (const float*)d_in[8];
    const float* beta  = (const float*)d_in[9];
    float* out = (float*)d_out;

    unsigned short* w1dt = (unsigned short*)d_ws;          //  64 KB
    unsigned short* w2t  = w1dt + 32768;                   // 128 KB
    unsigned short* wcst = w2t + 65536;                    // 128 KB
    unsigned short* cs   = wcst + 65536;                   // 15.36 MB (30000*256 bf16)
    unsigned short* sk   = cs + (long)NPTS * 256;          // 15.36 MB

    hipLaunchKernelGGL(prep_w, dim3(256), dim3(256), 0, stream, W1, W2, Ws, w1dt, w2t, wcst);
    hipLaunchKernelGGL(prep2, dim3(NPTS / 16), dim3(512), 0, stream,
                       feat, wcst, b1, b2, bs, cs, sk);
    hipLaunchKernelGGL(edgeconv_main, dim3(GRID), dim3(512), 0, stream,
                       feat, knn, w1dt, w2t, cs, sk, gamma, beta, out);
}

// Round 13
// 364.524 us; speedup vs baseline: 1.1486x; 1.0934x over previous
//
#include <hip/hip_runtime.h>
#include <hip/hip_bf16.h>
#include <math.h>

#define NPTS 30000
#define KNN  16
#define NB   15          // batches (of 4 points) per block
#define GRID 500         // 500 * 60 pts = 30000 exactly

typedef __attribute__((ext_vector_type(8)))  __bf16 bf16x8;
typedef __attribute__((ext_vector_type(16))) float  f32x16;
typedef __attribute__((ext_vector_type(4)))  float  f32x4;

__device__ __forceinline__ unsigned short f2bf(float x) {
    __bf16 b = (__bf16)x;                       // native cvt (RNE)
    return __builtin_bit_cast(unsigned short, b);
}
__device__ __forceinline__ unsigned pk2(float a, float b) {
    return (unsigned)f2bf(a) | ((unsigned)f2bf(b) << 16);
}
__device__ __forceinline__ float bf_lo(unsigned u) { return __builtin_bit_cast(float, u << 16); }
__device__ __forceinline__ float bf_hi(unsigned u) { return __builtin_bit_cast(float, u & 0xffff0000u); }
// tanh-form GELU: x*(1 - 1/(exp(1.5958*(x+0.044715x^3)) + 1))
__device__ __forceinline__ float gelu_t(float x) {
    float x2 = x * x;
    float u  = x * fmaf(0.07135481624f, x2, 1.59576912161f);
    float e  = __expf(u);
    float r  = __builtin_amdgcn_rcpf(e + 1.0f);
    return fmaf(-x, r, x);
}

// ---- prep1: bf16 weight layouts in ws ----
__global__ void prep_w(const float* __restrict__ W1, const float* __restrict__ W2,
                       const float* __restrict__ Ws,
                       unsigned short* __restrict__ w1dt, unsigned short* __restrict__ w2t,
                       unsigned short* __restrict__ wcst) {
    int t = blockIdx.x * 256 + threadIdx.x;          // t < 65536
    {   int e = t >> 8, c = t & 255;
        w2t[t] = f2bf(W2[c * 256 + e]); }
    {   int col = t >> 7, k = t & 127;
        float v = (col < 256) ? W1[k * 256 + col] : Ws[k * 256 + (col - 256)];
        wcst[t] = f2bf(v); }
    if (t < 32768) {
        int d = t >> 7, k = t & 127;
        w1dt[t] = f2bf(W1[(128 + k) * 256 + d]); }
}

// ---- prep2: per-point affine terms (cterm, skip) for ALL points ----
__global__ __launch_bounds__(512) void prep2(
    const float* __restrict__ feat, const unsigned short* __restrict__ wcst,
    const float* __restrict__ b1, const float* __restrict__ b2,
    const float* __restrict__ bs,
    unsigned short* __restrict__ cs, unsigned short* __restrict__ sk)
{
    const int lane = threadIdx.x & 63;
    const int wv   = threadIdx.x >> 6;
    const int l15  = lane & 15;
    const int l4   = lane >> 4;
    const int pb   = blockIdx.x * 16;                 // 1875 * 16 = 30000

    bf16x8 af[4];
    #pragma unroll
    for (int ks = 0; ks < 4; ++ks) {
        const float* fp = feat + (long)(pb + l15) * 128 + ks * 32 + l4 * 8;
        float4 f0 = *(const float4*)fp;
        float4 f1 = *(const float4*)(fp + 4);
        uint4 u;
        u.x = pk2(f0.x, f0.y); u.y = pk2(f0.z, f0.w);
        u.z = pk2(f1.x, f1.y); u.w = pk2(f1.z, f1.w);
        af[ks] = __builtin_bit_cast(bf16x8, u);
    }
    #pragma unroll
    for (int j = 0; j < 4; ++j) {
        const int ct  = wv * 4 + j;                   // 0..31
        const int col = ct * 16 + l15;
        float bias = (ct < 16) ? b1[col] : (bs[col - 256] + b2[col - 256]);
        f32x4 acc = {bias, bias, bias, bias};
        #pragma unroll
        for (int ks = 0; ks < 4; ++ks) {
            bf16x8 bf = *(const bf16x8*)(wcst + col * 128 + ks * 32 + l4 * 8);
            acc = __builtin_amdgcn_mfma_f32_16x16x32_bf16(af[ks], bf, acc, 0, 0, 0);
        }
        #pragma unroll
        for (int r = 0; r < 4; ++r) {
            const int n = pb + l4 * 4 + r;            // D row = point
            if (ct < 16) cs[(long)n * 256 + col]         = f2bf(acc[r]);
            else         sk[(long)n * 256 + (col - 256)] = f2bf(acc[r]);
        }
    }
}

// Lean BP=4 kernel, total regs (VGPR+AGPR) forced <=128 via launch_bounds(512,4)
// -> target 16 waves/CU (R12 evidence: without the bound, AGPRs push total >128
// and occupancy pins at 8 waves/CU regardless of LDS/VGPR).
// LDS 72 KB (edge dbuf 32 + h single 32 + agg dbuf 8) -> 2 blocks/CU.
// Per iter i, TWO barriers:
//  P1: issue ct(i)/sk(i-2) loads; B) GEMM2(i-1): h . W2(streamed) -> max -> agg[(i-1)&1]
//  [bar]  (h now free; agg(i-2) stable from prev iter)
//  P2: C) GEMM1(i): edge[i&1].W1d + ct -> gelu -> h; D) LN(i-2) -> out; F) stage(i+1)
//  [bar]
// Lifetimes: edge[p&1] W@F(p-1) R@C(p) W@F(p+1) (2 bars between R and next W);
// h W@C(i) R@B(i+1) (1 bar), next W@C(i+1) (1 bar after R); agg[p&1] W@B(p+1)
// R@D(p+2) (1 bar) next W@B(p+3) (2 bars after R).
__global__ __launch_bounds__(512, 4) void edgeconv_main(
    const float* __restrict__ feat, const int* __restrict__ knn,
    const unsigned short* __restrict__ w1dt, const unsigned short* __restrict__ w2t,
    const unsigned short* __restrict__ cs,  const unsigned short* __restrict__ sk,
    const float* __restrict__ gamma, const float* __restrict__ beta,
    float* __restrict__ out)
{
    __shared__ __align__(16) unsigned char  s_edge[2][64 * 256];   // 32 KB, swz (row&15)<<4
    __shared__ __align__(16) unsigned char  s_h[64 * 512];         // 32 KB single buf, swz (row&31)<<4
    __shared__ __align__(16) float s_agg[2][4][256];               //  8 KB
    // total 72 KB -> 2 blocks/CU

    const int lane = threadIdx.x & 63;
    const int wv   = threadIdx.x >> 6;      // 0..7
    const int l31  = lane & 31;
    const int lh   = lane >> 5;
    const int pblock = blockIdx.x * 60;
    const int chb = wv * 32;                // this wave's 32 channels (both GEMMs)

    // persistent: W1d fragments only (32 VGPR)
    bf16x8 w1f[8];
    #pragma unroll
    for (int ks = 0; ks < 8; ++ks)
        w1f[ks] = *(const bf16x8*)(w1dt + (chb + l31) * 128 + ks * 16 + lh * 8);

    // staging role: wave stages 8 rows of point (wv>>1), neighbors (wv&1)*8..+8
    const int st_pt = wv >> 1;
    const int st_kb = (wv & 1) * 8;

    auto stage = [&](int bt) {
        const int n = pblock + bt * 4 + st_pt;
        float2 cc = *(const float2*)(feat + (long)n * 128 + lane * 2);
        int4 iv0 = *(const int4*)(knn + n * 16 + st_kb);
        int4 iv1 = *(const int4*)(knn + n * 16 + st_kb + 4);
        int idx[8] = {iv0.x, iv0.y, iv0.z, iv0.w, iv1.x, iv1.y, iv1.z, iv1.w};
        #pragma unroll
        for (int kk = 0; kk < 8; ++kk) {
            float2 nb = *(const float2*)(feat + (long)idx[kk] * 128 + lane * 2);
            int row = st_pt * 16 + st_kb + kk;
            unsigned v = pk2(nb.x - cc.x, nb.y - cc.y);
            *(unsigned*)(s_edge[bt & 1] + row * 256 + ((unsigned)(lane * 4) ^ (unsigned)((row & 15) << 4))) = v;
        }
    };

    // ---- prologue ----
    stage(0);
    __syncthreads();

    const f32x16 z16 = (f32x16)0.0f;

    #pragma unroll 1
    for (int i = 0; i <= NB + 1; ++i) {
        // ==================== P1 ====================
        // issue cterm loads for C(i): lane covers points rowb*2 + (l31>>4)
        uint2 ct4[2][4];
        if (i < NB) {
            #pragma unroll
            for (int rowb = 0; rowb < 2; ++rowb) {
                const int n_pt = pblock + i * 4 + rowb * 2 + (l31 >> 4);
                const unsigned short* cp = cs + (long)n_pt * 256 + chb + 4 * lh;
                #pragma unroll
                for (int g = 0; g < 4; ++g) ct4[rowb][g] = *(const uint2*)(cp + 8 * g);
            }
        }
        uint2 skv;                           // skip for D(i-2): point pblock+(i-2)*4+wv
        if (i >= 2 && wv < 4) {
            const int n = pblock + (i - 2) * 4 + wv;
            skv = *(const uint2*)(sk + (long)n * 256 + lane * 4);
        }

        // ---- B) GEMM2(i-1): eo = h . W2 (streamed); max over 16 rows -> s_agg ----
        if (i >= 1 && i <= NB) {
            const int bt = i - 1;
            const unsigned short* w2p = w2t + (chb + l31) * 256 + lh * 8;
            asm volatile("" : "+v"(w2p));    // keep W2 frags transient (reg budget)
            f32x16 a2[2] = {z16, z16};
            #pragma unroll
            for (int half = 0; half < 4; ++half) {
                bf16x8 wf[4];
                #pragma unroll
                for (int k = 0; k < 4; ++k)
                    wf[k] = *(const bf16x8*)(w2p + (half * 4 + k) * 16);
                #pragma unroll
                for (int k = 0; k < 4; ++k) {
                    const int ks = half * 4 + k;
                    #pragma unroll
                    for (int rowb = 0; rowb < 2; ++rowb) {
                        const int row = rowb * 32 + l31;
                        const unsigned swz = (unsigned)((row & 31) << 4);
                        bf16x8 hf = *(const bf16x8*)(s_h + (unsigned)row * 512u + ((unsigned)(ks * 32 + lh * 16) ^ swz));
                        a2[rowb] = __builtin_amdgcn_mfma_f32_32x32x16_bf16(hf, wf[k], a2[rowb], 0, 0, 0);
                    }
                }
            }
            #pragma unroll
            for (int rowb = 0; rowb < 2; ++rowb) {
                float m0 = a2[rowb][0], m1 = a2[rowb][8];
                #pragma unroll
                for (int r = 1; r < 8; ++r) {
                    m0 = fmaxf(m0, a2[rowb][r]);        // pt 2*rowb
                    m1 = fmaxf(m1, a2[rowb][8 + r]);    // pt 2*rowb+1
                }
                m0 = fmaxf(m0, __shfl_xor(m0, 32));
                m1 = fmaxf(m1, __shfl_xor(m1, 32));
                if (lh == 0) {
                    s_agg[bt & 1][rowb * 2 + 0][chb + l31] = m0;
                    s_agg[bt & 1][rowb * 2 + 1][chb + l31] = m1;
                }
            }
        }
        __syncthreads();   // h free; agg(i-1) visible

        // ==================== P2 ====================
        // ---- C) GEMM1(i): h = gelu(edge_diff . W1d + cterm) -> s_h ----
        if (i < NB) {
            f32x16 acc1[2] = {z16, z16};
            #pragma unroll
            for (int rowb = 0; rowb < 2; ++rowb) {
                const int row = rowb * 32 + l31;
                const unsigned swz = (unsigned)((row & 15) << 4);
                const unsigned rb = (unsigned)row * 256u;
                #pragma unroll
                for (int ks = 0; ks < 8; ++ks) {
                    bf16x8 bf = *(const bf16x8*)(s_edge[i & 1] + rb + ((unsigned)(ks * 32 + lh * 16) ^ swz));
                    acc1[rowb] = __builtin_amdgcn_mfma_f32_32x32x16_bf16(w1f[ks], bf, acc1[rowb], 0, 0, 0);
                }
            }
            #pragma unroll
            for (int rowb = 0; rowb < 2; ++rowb) {
                const int row = rowb * 32 + l31;
                const unsigned swz = (unsigned)((row & 31) << 4);
                #pragma unroll
                for (int g = 0; g < 4; ++g) {
                    const int ch0 = chb + 8 * g + 4 * lh;
                    float v0 = gelu_t(acc1[rowb][4 * g + 0] + bf_lo(ct4[rowb][g].x));
                    float v1 = gelu_t(acc1[rowb][4 * g + 1] + bf_hi(ct4[rowb][g].x));
                    float v2 = gelu_t(acc1[rowb][4 * g + 2] + bf_lo(ct4[rowb][g].y));
                    float v3 = gelu_t(acc1[rowb][4 * g + 3] + bf_hi(ct4[rowb][g].y));
                    uint2 hv; hv.x = pk2(v0, v1); hv.y = pk2(v2, v3);
                    *(uint2*)(s_h + (unsigned)row * 512u + ((unsigned)(ch0 * 2) ^ swz)) = hv;
                }
            }
        }

        // ---- D) LayerNorm(i-2) on waves 0-3 ----
        if (i >= 2 && wv < 4) {
            const int bt2 = i - 2;
            const int n   = pblock + bt2 * 4 + wv;
            float4 ag = *(const float4*)&s_agg[bt2 & 1][wv][lane * 4];
            float x0 = ag.x + bf_lo(skv.x), x1 = ag.y + bf_hi(skv.x);
            float x2 = ag.z + bf_lo(skv.y), x3 = ag.w + bf_hi(skv.y);
            float s  = x0 + x1 + x2 + x3;
            float ss = fmaf(x0, x0, fmaf(x1, x1, fmaf(x2, x2, x3 * x3)));
            #pragma unroll
            for (int off = 1; off < 64; off <<= 1) {
                s  += __shfl_xor(s, off);
                ss += __shfl_xor(ss, off);
            }
            float mu   = s * (1.0f / 256.0f);
            float var  = ss * (1.0f / 256.0f) - mu * mu;
            float rstd = rsqrtf(var + 1e-5f);
            float4 g4 = *(const float4*)&gamma[lane * 4];
            float4 b4 = *(const float4*)&beta[lane * 4];
            float4 o;
            o.x = (x0 - mu) * rstd * g4.x + b4.x;
            o.y = (x1 - mu) * rstd * g4.y + b4.y;
            o.z = (x2 - mu) * rstd * g4.z + b4.z;
            o.w = (x3 - mu) * rstd * g4.w + b4.w;
            *(float4*)&out[(long)n * 256 + lane * 4] = o;
        }

        // ---- F) stage batch i+1 -> edge[(i+1)&1] ----
        if (i + 1 < NB) stage(i + 1);

        __syncthreads();
    }
}

extern "C" void kernel_launch(void* const* d_in, const int* in_sizes, int n_in,
                              void* d_out, int out_size, void* d_ws, size_t ws_size,
                              hipStream_t stream) {
    const float* feat  = (const float*)d_in[0];
    const int*   knn   = (const int*)  d_in[1];
    const float* W1    = (const float*)d_in[2];
    const float* b1    = (const float*)d_in[3];
    const float* W2    = (const float*)d_in[4];
    const float* b2    = (const float*)d_in[5];
    const float* Ws    = (const float*)d_in[6];
    const float* bs    = (const float*)d_in[7];
    const float* gamma = (const float*)d_in[8];
    const float* beta  = (const float*)d_in[9];
    float* out = (float*)d_out;

    unsigned short* w1dt = (unsigned short*)d_ws;          //  64 KB
    unsigned short* w2t  = w1dt + 32768;                   // 128 KB
    unsigned short* wcst = w2t + 65536;                    // 128 KB
    unsigned short* cs   = wcst + 65536;                   // 15.36 MB
    unsigned short* sk   = cs + (long)NPTS * 256;          // 15.36 MB

    hipLaunchKernelGGL(prep_w, dim3(256), dim3(256), 0, stream, W1, W2, Ws, w1dt, w2t, wcst);
    hipLaunchKernelGGL(prep2, dim3(NPTS / 16), dim3(512), 0, stream,
                       feat, wcst, b1, b2, bs, cs, sk);
    hipLaunchKernelGGL(edgeconv_main, dim3(GRID), dim3(512), 0, stream,
                       feat, knn, w1dt, w2t, cs, sk, gamma, beta, out);
}

// Round 15
// 329.480 us; speedup vs baseline: 1.2708x; 1.1064x over previous
//
#include <hip/hip_runtime.h>
#include <hip/hip_bf16.h>
#include <math.h>

#define NPTS 30000
#define KNN  16
#define NB   15          // batches (of 4 points) per block
#define GRID 500         // 500 * 60 pts = 30000 exactly

typedef __attribute__((ext_vector_type(8)))  __bf16 bf16x8;
typedef __attribute__((ext_vector_type(16))) float  f32x16;
typedef __attribute__((ext_vector_type(4)))  float  f32x4;

__device__ __forceinline__ unsigned short f2bf(float x) {
    __bf16 b = (__bf16)x;                       // native cvt (RNE)
    return __builtin_bit_cast(unsigned short, b);
}
__device__ __forceinline__ unsigned pk2(float a, float b) {
    return (unsigned)f2bf(a) | ((unsigned)f2bf(b) << 16);
}
__device__ __forceinline__ float bf_lo(unsigned u) { return __builtin_bit_cast(float, u << 16); }
__device__ __forceinline__ float bf_hi(unsigned u) { return __builtin_bit_cast(float, u & 0xffff0000u); }
// tanh-form GELU: x*(1 - 1/(exp(1.5958*(x+0.044715x^3)) + 1))
__device__ __forceinline__ float gelu_t(float x) {
    float x2 = x * x;
    float u  = x * fmaf(0.07135481624f, x2, 1.59576912161f);
    float e  = __expf(u);
    float r  = __builtin_amdgcn_rcpf(e + 1.0f);
    return fmaf(-x, r, x);
}

// ---- prep1: bf16 weight layouts in ws ----
__global__ void prep_w(const float* __restrict__ W1, const float* __restrict__ W2,
                       const float* __restrict__ Ws,
                       unsigned short* __restrict__ w1dt, unsigned short* __restrict__ w2t,
                       unsigned short* __restrict__ wcst) {
    int t = blockIdx.x * 256 + threadIdx.x;          // t < 65536
    {   int e = t >> 8, c = t & 255;
        w2t[t] = f2bf(W2[c * 256 + e]); }
    {   int col = t >> 7, k = t & 127;
        float v = (col < 256) ? W1[k * 256 + col] : Ws[k * 256 + (col - 256)];
        wcst[t] = f2bf(v); }
    if (t < 32768) {
        int d = t >> 7, k = t & 127;
        w1dt[t] = f2bf(W1[(128 + k) * 256 + d]); }
}

// ---- prep2: per-point affine terms (cterm, skip) for ALL points ----
__global__ __launch_bounds__(512) void prep2(
    const float* __restrict__ feat, const unsigned short* __restrict__ wcst,
    const float* __restrict__ b1, const float* __restrict__ b2,
    const float* __restrict__ bs,
    unsigned short* __restrict__ cs, unsigned short* __restrict__ sk)
{
    const int lane = threadIdx.x & 63;
    const int wv   = threadIdx.x >> 6;
    const int l15  = lane & 15;
    const int l4   = lane >> 4;
    const int pb   = blockIdx.x * 16;                 // 1875 * 16 = 30000

    bf16x8 af[4];
    #pragma unroll
    for (int ks = 0; ks < 4; ++ks) {
        const float* fp = feat + (long)(pb + l15) * 128 + ks * 32 + l4 * 8;
        float4 f0 = *(const float4*)fp;
        float4 f1 = *(const float4*)(fp + 4);
        uint4 u;
        u.x = pk2(f0.x, f0.y); u.y = pk2(f0.z, f0.w);
        u.z = pk2(f1.x, f1.y); u.w = pk2(f1.z, f1.w);
        af[ks] = __builtin_bit_cast(bf16x8, u);
    }
    #pragma unroll
    for (int j = 0; j < 4; ++j) {
        const int ct  = wv * 4 + j;                   // 0..31
        const int col = ct * 16 + l15;
        float bias = (ct < 16) ? b1[col] : (bs[col - 256] + b2[col - 256]);
        f32x4 acc = {bias, bias, bias, bias};
        #pragma unroll
        for (int ks = 0; ks < 4; ++ks) {
            bf16x8 bf = *(const bf16x8*)(wcst + col * 128 + ks * 32 + l4 * 8);
            acc = __builtin_amdgcn_mfma_f32_16x16x32_bf16(af[ks], bf, acc, 0, 0, 0);
        }
        #pragma unroll
        for (int r = 0; r < 4; ++r) {
            const int n = pb + l4 * 4 + r;            // D row = point
            if (ct < 16) cs[(long)n * 256 + col]         = f2bf(acc[r]);
            else         sk[(long)n * 256 + (col - 256)] = f2bf(acc[r]);
        }
    }
}

// R13 with ONE structural delta: rowb hoisted outermost in BOTH GEMMs so only
// one f32x16 accumulator (16 AGPR) is live at a time, and ct4 halves to 8 VGPR
// loaded at use. Per-rowb math byte-identical to R13. Targets R13's spill
// (WRITE 78MB / FETCH 446MB) under the launch_bounds(512,4) reg cap.
__global__ __launch_bounds__(512, 4) void edgeconv_main(
    const float* __restrict__ feat, const int* __restrict__ knn,
    const unsigned short* __restrict__ w1dt, const unsigned short* __restrict__ w2t,
    const unsigned short* __restrict__ cs,  const unsigned short* __restrict__ sk,
    const float* __restrict__ gamma, const float* __restrict__ beta,
    float* __restrict__ out)
{
    __shared__ __align__(16) unsigned char  s_edge[2][64 * 256];   // 32 KB, swz (row&15)<<4
    __shared__ __align__(16) unsigned char  s_h[64 * 512];         // 32 KB single buf, swz (row&31)<<4
    __shared__ __align__(16) float s_agg[2][4][256];               //  8 KB
    // total 72 KB -> 2 blocks/CU

    const int lane = threadIdx.x & 63;
    const int wv   = threadIdx.x >> 6;      // 0..7
    const int l31  = lane & 31;
    const int lh   = lane >> 5;
    const int pblock = blockIdx.x * 60;
    const int chb = wv * 32;                // this wave's 32 channels (both GEMMs)

    // persistent: W1d fragments (32 VGPR) — proven correct R13
    bf16x8 w1f[8];
    #pragma unroll
    for (int ks = 0; ks < 8; ++ks)
        w1f[ks] = *(const bf16x8*)(w1dt + (chb + l31) * 128 + ks * 16 + lh * 8);

    // staging role: wave stages 8 rows of point (wv>>1), neighbors (wv&1)*8..+8
    const int st_pt = wv >> 1;
    const int st_kb = (wv & 1) * 8;

    auto stage = [&](int bt) {
        const int n = pblock + bt * 4 + st_pt;
        float2 cc = *(const float2*)(feat + (long)n * 128 + lane * 2);
        int4 iv0 = *(const int4*)(knn + n * 16 + st_kb);
        int4 iv1 = *(const int4*)(knn + n * 16 + st_kb + 4);
        int idx[8] = {iv0.x, iv0.y, iv0.z, iv0.w, iv1.x, iv1.y, iv1.z, iv1.w};
        #pragma unroll
        for (int kk = 0; kk < 8; ++kk) {
            float2 nb = *(const float2*)(feat + (long)idx[kk] * 128 + lane * 2);
            int row = st_pt * 16 + st_kb + kk;
            unsigned v = pk2(nb.x - cc.x, nb.y - cc.y);
            *(unsigned*)(s_edge[bt & 1] + row * 256 + ((unsigned)(lane * 4) ^ (unsigned)((row & 15) << 4))) = v;
        }
    };

    // ---- prologue ----
    stage(0);
    __syncthreads();

    const f32x16 z16 = (f32x16)0.0f;

    #pragma unroll 1
    for (int i = 0; i <= NB + 1; ++i) {
        // ==================== P1 ====================
        // ---- B) GEMM2(i-1): eo = h . W2 (streamed); rowb outermost ----
        if (i >= 1 && i <= NB) {
            const int bt = i - 1;
            #pragma unroll 1
            for (int rowb = 0; rowb < 2; ++rowb) {
                const int row = rowb * 32 + l31;
                const unsigned swz = (unsigned)((row & 31) << 4);
                const unsigned rb = (unsigned)row * 512u;
                const unsigned short* w2p = w2t + (chb + l31) * 256 + lh * 8;
                asm volatile("" : "+v"(w2p));    // keep W2 frags transient
                f32x16 a2 = z16;
                #pragma unroll
                for (int half = 0; half < 4; ++half) {
                    bf16x8 wf[4];
                    #pragma unroll
                    for (int k = 0; k < 4; ++k)
                        wf[k] = *(const bf16x8*)(w2p + (half * 4 + k) * 16);
                    #pragma unroll
                    for (int k = 0; k < 4; ++k) {
                        const int ks = half * 4 + k;
                        bf16x8 hf = *(const bf16x8*)(s_h + rb + ((unsigned)(ks * 32 + lh * 16) ^ swz));
                        a2 = __builtin_amdgcn_mfma_f32_32x32x16_bf16(hf, wf[k], a2, 0, 0, 0);
                    }
                }
                float m0 = a2[0], m1 = a2[8];
                #pragma unroll
                for (int r = 1; r < 8; ++r) {
                    m0 = fmaxf(m0, a2[r]);        // pt 2*rowb
                    m1 = fmaxf(m1, a2[8 + r]);    // pt 2*rowb+1
                }
                m0 = fmaxf(m0, __shfl_xor(m0, 32));
                m1 = fmaxf(m1, __shfl_xor(m1, 32));
                if (lh == 0) {
                    s_agg[bt & 1][rowb * 2 + 0][chb + l31] = m0;
                    s_agg[bt & 1][rowb * 2 + 1][chb + l31] = m1;
                }
            }
        }
        __syncthreads();   // h free; agg(i-1) visible

        // ==================== P2 ====================
        // ---- C) GEMM1(i): h = gelu(edge . W1d + cterm); rowb outermost ----
        if (i < NB) {
            #pragma unroll 1
            for (int rowb = 0; rowb < 2; ++rowb) {
                const int row = rowb * 32 + l31;
                // cterm for this rowb's point (8 VGPR, loaded at use)
                const int n_pt = pblock + i * 4 + rowb * 2 + (l31 >> 4);
                const unsigned short* cp = cs + (long)n_pt * 256 + chb + 4 * lh;
                uint2 ct4[4];
                #pragma unroll
                for (int g = 0; g < 4; ++g) ct4[g] = *(const uint2*)(cp + 8 * g);

                f32x16 acc1 = z16;
                {
                    const unsigned swz = (unsigned)((row & 15) << 4);
                    const unsigned rb = (unsigned)row * 256u;
                    #pragma unroll
                    for (int ks = 0; ks < 8; ++ks) {
                        bf16x8 bf = *(const bf16x8*)(s_edge[i & 1] + rb + ((unsigned)(ks * 32 + lh * 16) ^ swz));
                        acc1 = __builtin_amdgcn_mfma_f32_32x32x16_bf16(w1f[ks], bf, acc1, 0, 0, 0);
                    }
                }
                {
                    const unsigned swz = (unsigned)((row & 31) << 4);
                    #pragma unroll
                    for (int g = 0; g < 4; ++g) {
                        const int ch0 = chb + 8 * g + 4 * lh;
                        float v0 = gelu_t(acc1[4 * g + 0] + bf_lo(ct4[g].x));
                        float v1 = gelu_t(acc1[4 * g + 1] + bf_hi(ct4[g].x));
                        float v2 = gelu_t(acc1[4 * g + 2] + bf_lo(ct4[g].y));
                        float v3 = gelu_t(acc1[4 * g + 3] + bf_hi(ct4[g].y));
                        uint2 hv; hv.x = pk2(v0, v1); hv.y = pk2(v2, v3);
                        *(uint2*)(s_h + (unsigned)row * 512u + ((unsigned)(ch0 * 2) ^ swz)) = hv;
                    }
                }
            }
        }

        // ---- D) LayerNorm(i-2) on waves 0-3 ----
        if (i >= 2 && wv < 4) {
            const int bt2 = i - 2;
            const int n   = pblock + bt2 * 4 + wv;
            uint2 skv = *(const uint2*)(sk + (long)n * 256 + lane * 4);
            float4 ag = *(const float4*)&s_agg[bt2 & 1][wv][lane * 4];
            float x0 = ag.x + bf_lo(skv.x), x1 = ag.y + bf_hi(skv.x);
            float x2 = ag.z + bf_lo(skv.y), x3 = ag.w + bf_hi(skv.y);
            float s  = x0 + x1 + x2 + x3;
            float ss = fmaf(x0, x0, fmaf(x1, x1, fmaf(x2, x2, x3 * x3)));
            #pragma unroll
            for (int off = 1; off < 64; off <<= 1) {
                s  += __shfl_xor(s, off);
                ss += __shfl_xor(ss, off);
            }
            float mu   = s * (1.0f / 256.0f);
            float var  = ss * (1.0f / 256.0f) - mu * mu;
            float rstd = rsqrtf(var + 1e-5f);
            float4 g4 = *(const float4*)&gamma[lane * 4];
            float4 b4 = *(const float4*)&beta[lane * 4];
            float4 o;
            o.x = (x0 - mu) * rstd * g4.x + b4.x;
            o.y = (x1 - mu) * rstd * g4.y + b4.y;
            o.z = (x2 - mu) * rstd * g4.z + b4.z;
            o.w = (x3 - mu) * rstd * g4.w + b4.w;
            *(float4*)&out[(long)n * 256 + lane * 4] = o;
        }

        // ---- F) stage batch i+1 -> edge[(i+1)&1] ----
        if (i + 1 < NB) stage(i + 1);

        __syncthreads();
    }
}

extern "C" void kernel_launch(void* const* d_in, const int* in_sizes, int n_in,
                              void* d_out, int out_size, void* d_ws, size_t ws_size,
                              hipStream_t stream) {
    const float* feat  = (const float*)d_in[0];
    const int*   knn   = (const int*)  d_in[1];
    const float* W1    = (const float*)d_in[2];
    const float* b1    = (const float*)d_in[3];
    const float* W2    = (const float*)d_in[4];
    const float* b2    = (const float*)d_in[5];
    const float* Ws    = (const float*)d_in[6];
    const float* bs    = (const float*)d_in[7];
    const float* gamma = (const float*)d_in[8];
    const float* beta  = (const float*)d_in[9];
    float* out = (float*)d_out;

    unsigned short* w1dt = (unsigned short*)d_ws;          //  64 KB
    unsigned short* w2t  = w1dt + 32768;                   // 128 KB
    unsigned short* wcst = w2t + 65536;                    // 128 KB
    unsigned short* cs   = wcst + 65536;                   // 15.36 MB
    unsigned short* sk   = cs + (long)NPTS * 256;          // 15.36 MB

    hipLaunchKernelGGL(prep_w, dim3(256), dim3(256), 0, stream, W1, W2, Ws, w1dt, w2t, wcst);
    hipLaunchKernelGGL(prep2, dim3(NPTS / 16), dim3(512), 0, stream,
                       feat, wcst, b1, b2, bs, cs, sk);
    hipLaunchKernelGGL(edgeconv_main, dim3(GRID), dim3(512), 0, stream,
                       feat, knn, w1dt, w2t, cs, sk, gamma, beta, out);
}